// Round 11
// baseline (430.828 us; speedup 1.0000x reference)
//
#include <hip/hip_runtime.h>
#include <hip/hip_bf16.h>

// Dims
#define NB 4
#define NN 10000
#define NE 320000
#define BN 40000   // NB*NN
#define NL 7

typedef float f32x4 __attribute__((ext_vector_type(4)));
typedef __bf16 bf16x8 __attribute__((ext_vector_type(8)));

__device__ __forceinline__ float bf2f(unsigned short u){
  unsigned x = ((unsigned)u) << 16;
  return __builtin_bit_cast(float, x);
}
__device__ __forceinline__ unsigned short f2bf(float f){
  unsigned u = __builtin_bit_cast(unsigned, f);
  u += 0x7fffu + ((u >> 16) & 1u);
  return (unsigned short)(u >> 16);
}
__device__ __forceinline__ bf16x8 zero8(){
  uint4 z = make_uint4(0u,0u,0u,0u);
  return __builtin_bit_cast(bf16x8, z);
}
__device__ __forceinline__ bf16x8 one8(){
  // bf16 1.0 in element 0 (k=16 constant-1 bias channel), rest zero
  uint4 z = make_uint4(0x3f80u,0u,0u,0u);
  return __builtin_bit_cast(bf16x8, z);
}
__device__ __forceinline__ bf16x8 ld8bf(const unsigned short* p){
  uint4 u = *(const uint4*)p;
  return __builtin_bit_cast(bf16x8, u);
}
// packed RNE f32->bf16 pair: 1 instr instead of ~8 integer ops
__device__ __forceinline__ unsigned pk2(float lo, float hi){
  unsigned r;
  asm("v_cvt_pk_bf16_f32 %0, %1, %2" : "=v"(r) : "v"(lo), "v"(hi));
  return r;
}
__device__ __forceinline__ bf16x8 ld8f(const float* p){
  float4 a = *(const float4*)p;
  float4 b = *(const float4*)(p+4);
  uint4 u = make_uint4(pk2(a.x,a.y), pk2(a.z,a.w), pk2(b.x,b.y), pk2(b.z,b.w));
  return __builtin_bit_cast(bf16x8, u);
}
__device__ __forceinline__ float frcp(float x){ return __builtin_amdgcn_rcpf(x); }
__device__ __forceinline__ float tanh_(float x){ return 1.f - 2.f*frcp(__expf(2.f*x)+1.f); }
__device__ __forceinline__ float lrelu(float x){ return x > 0.f ? x : 0.01f*x; }

#define LDS_WAIT() asm volatile("s_waitcnt lgkmcnt(0)" ::: "memory")

// Prepped bf16 weight-table offsets (in d_out scratch, overwritten at the end
// by aggr_final — weights are dead by then). Layout per conv set:
//   W1T[64][96] (6144) + W2T[64][64] (4096) = 10240 elems.
// Sets: e0, e1, g0, g1, then uv WT[128][64] (8192). Total 49152 elems = 96KB.
#define WT_SET   10240
#define WT_UV    40960
#define WT_TOTAL 49152

// ---------------------------------------------------------------------------
// Fused 2-layer GCN MLP body (device fn). Weights read as bf16 fragments
// DIRECTLY from the prepped global table (L2-hot) — no staging, no barrier.
// ---------------------------------------------------------------------------
__device__ __forceinline__ void mlp2_body(
    int bid,
    const float* __restrict__ x,            // [BN][64] f32
    const int* __restrict__ ntid,           // [NN]
    const float* __restrict__ emb,          // [3][16]
    const unsigned short* __restrict__ W1T, // [64][96] bf16 (prepped)
    const float* __restrict__ b1,           // [64]
    const unsigned short* __restrict__ W2T, // [64][64] bf16 (prepped)
    const float* __restrict__ b2,           // [64]
    unsigned short* __restrict__ out)       // [BN][64] bf16
{
  __shared__ __attribute__((aligned(16))) unsigned short hb[4][16][72];
  int tid = threadIdx.x;
  int wave = tid>>6, lane = tid&63, ln16 = lane&15, quad = lane>>4;
  int row0 = bid*64 + wave*16;
  int r_ = row0 + ln16;
  const float* xr = x + (size_t)r_*64;
  bf16x8 a0 = ld8f(xr + quad*8);
  bf16x8 a1 = ld8f(xr + 32 + quad*8);
  int id = ntid[r_ % NN];
  bf16x8 a2 = (quad<2) ? ld8f(emb + id*16 + quad*8) : zero8();

  f32x4 acc[4];
  #pragma unroll
  for (int nt=0;nt<4;++nt){
    float bb = b1[nt*16+ln16];
    acc[nt] = (f32x4){bb,bb,bb,bb};
    acc[nt] = __builtin_amdgcn_mfma_f32_16x16x32_bf16(a0, ld8bf(W1T + (nt*16+ln16)*96 + quad*8),      acc[nt], 0,0,0);
    acc[nt] = __builtin_amdgcn_mfma_f32_16x16x32_bf16(a1, ld8bf(W1T + (nt*16+ln16)*96 + 32 + quad*8), acc[nt], 0,0,0);
    acc[nt] = __builtin_amdgcn_mfma_f32_16x16x32_bf16(a2, ld8bf(W1T + (nt*16+ln16)*96 + 64 + quad*8), acc[nt], 0,0,0);
  }
  #pragma unroll
  for (int nt=0;nt<4;++nt)
    #pragma unroll
    for (int i=0;i<4;++i)
      hb[wave][quad*4+i][nt*16+ln16] = f2bf(lrelu(acc[nt][i]));
  LDS_WAIT();
  bf16x8 h0 = ld8bf(&hb[wave][ln16][quad*8]);
  bf16x8 h1 = ld8bf(&hb[wave][ln16][32+quad*8]);
  f32x4 acc2[4];
  #pragma unroll
  for (int nt=0;nt<4;++nt){
    float bb = b2[nt*16+ln16];
    acc2[nt] = (f32x4){bb,bb,bb,bb};
    acc2[nt] = __builtin_amdgcn_mfma_f32_16x16x32_bf16(h0, ld8bf(W2T + (nt*16+ln16)*64 + quad*8),      acc2[nt], 0,0,0);
    acc2[nt] = __builtin_amdgcn_mfma_f32_16x16x32_bf16(h1, ld8bf(W2T + (nt*16+ln16)*64 + 32 + quad*8), acc2[nt], 0,0,0);
  }
  #pragma unroll
  for (int nt=0;nt<4;++nt)
    #pragma unroll
    for (int i=0;i<4;++i)
      out[(size_t)(row0+quad*4+i)*64 + nt*16+ln16] = f2bf(lrelu(acc2[nt][i]));
}

// ---------------------------------------------------------------------------
// GRU (R5 structure — measured latency floor ~76-81us, grid-limited)
// FUSED with count (blocks 625-1874) and weight-prep (blocks 1875-1882).
// DEAD ENDS: Wx-frag hoist spill (107us); 320-thr blocks (95us); pure-reg
// h recurrence (78-81us); (256,3) scratch spill (147us); WxT stride 32
// 8-way conflicts; R7 pass-based fused gather (+26us).
// ---------------------------------------------------------------------------
__global__ __launch_bounds__(256, 2) void gru_count_kernel(
    const float* __restrict__ xd,   // [BN][256] f32 (T*DIN)
    const float* __restrict__ Wx,   // [16][192]
    const float* __restrict__ Wh,   // [64][192]
    const float* __restrict__ bx,   // [192]
    const float* __restrict__ bh,   // [192]
    float* __restrict__ rnn,        // [BN][64] f32 (max over T)
    const int* __restrict__ ei,
    int* __restrict__ counts,
    const float* __restrict__ ec0W1, const float* __restrict__ ec0W2,
    const float* __restrict__ ec1W1, const float* __restrict__ ec1W2,
    const float* __restrict__ gc0W1, const float* __restrict__ gc0W2,
    const float* __restrict__ gc1W1, const float* __restrict__ gc1W2,
    const float* __restrict__ efmW1,
    unsigned short* __restrict__ wt)
{
  if (blockIdx.x >= 1875){
    // weight prep: 8 blocks x 256 thr
    int pidx = blockIdx.x - 1875;
    for (int i = pidx*256 + threadIdx.x; i < WT_TOTAL; i += 2048){
      unsigned short v;
      if (i < WT_UV){
        int s = i / WT_SET, j = i - s*WT_SET;
        const float* W1s = (s==0) ? ec0W1 : (s==1) ? ec1W1 : (s==2) ? gc0W1 : gc1W1;
        const float* W2s = (s==0) ? ec0W2 : (s==1) ? ec1W2 : (s==2) ? gc0W2 : gc1W2;
        if (j < 6144){
          int n = j / 96, k = j - n*96;
          v = (k < 80) ? f2bf(W1s[k*64+n]) : (unsigned short)0;
        } else {
          int j2 = j - 6144;
          int n = j2 >> 6, k = j2 & 63;
          v = f2bf(W2s[k*64+n]);
        }
      } else {
        int j = i - WT_UV;
        int n = j >> 6, k = j & 63;
        v = f2bf((n < 64) ? efmW1[k*64+n] : efmW1[4096 + k*64 + (n-64)]);
      }
      wt[i] = v;
    }
    return;
  }
  if (blockIdx.x >= 625){
    int e = (blockIdx.x-625)*256 + threadIdx.x;
    atomicAdd(&counts[ei[NE+e]], 1);
    return;
  }
  __shared__ __attribute__((aligned(16))) unsigned short WhT[192][72];
  __shared__ __attribute__((aligned(16))) unsigned short WxT[192][40]; // k16=bias, k17..32 zero
  __shared__ __attribute__((aligned(16))) unsigned short hb[4][16][76]; // [row r][hdim], padded
  int tid = threadIdx.x;
  int wave = tid >> 6, lane = tid & 63;
  int ln16 = lane & 15, quad = lane >> 4;

  for (int i = tid; i < 64*192; i += 256){
    int k = i / 192, n = i - k*192;
    WhT[n][k] = f2bf(Wh[i]);
  }
  for (int i = tid; i < 16*192; i += 256){
    int k = i / 192, n = i - k*192;
    WxT[n][k] = f2bf(Wx[i]);
    WxT[n][17+k] = 0;                 // zero k17..32 (k24..31 read by quad 3)
  }
  if (tid < 192){
    // bias channel: r/z gates get bx+bh, n-gate x-part gets bx only
    float bias = (tid < 128) ? (bx[tid] + bh[tid]) : bx[tid];
    WxT[tid][16] = f2bf(bias);
  }
  for (int i = tid; i < 4*16*76; i += 256) ((unsigned short*)hb)[i] = 0;
  __syncthreads();   // the only block barrier

  int rowbase = blockIdx.x * 64 + wave * 16;

  bf16x8 whf[2][12];
  #pragma unroll
  for (int kt=0; kt<2; ++kt)
    #pragma unroll
    for (int nt=0; nt<12; ++nt)
      whf[kt][nt] = ld8bf(&WhT[nt*16 + ln16][kt*32 + quad*8]);

  f32x4 bhn2[4];
  #pragma unroll
  for (int j=0;j<4;++j)
    bhn2[j] = *(const f32x4*)(bh + 128 + j*16 + quad*4);

  f32x4 hprev[4], vmax[4];
  #pragma unroll
  for (int j=0;j<4;++j){
    hprev[j] = (f32x4){0.f,0.f,0.f,0.f};
    vmax[j]  = (f32x4){-1e30f,-1e30f,-1e30f,-1e30f};
  }

  const float* xrow = xd + (size_t)(rowbase + ln16) * 256;
  unsigned short* hrow = &hb[wave][ln16][0];

  bf16x8 axc;
  if (quad < 2) axc = ld8f(xrow + quad*8);
  else          axc = (quad == 2) ? one8() : zero8();

  for (int t = 0; t < 16; ++t){
    bf16x8 axn;
    if (quad < 2) axn = (t < 15) ? ld8f(xrow + (t+1)*16 + quad*8) : zero8();
    else          axn = (quad == 2) ? one8() : zero8();
    bf16x8 ah0 = ld8bf(hrow + quad*8);        // B frag: h[r=ln16][k=quad*8+e]
    bf16x8 ah1 = ld8bf(hrow + 32 + quad*8);

    #pragma unroll
    for (int j=0;j<4;++j){
      bf16x8 xr = ld8bf(&WxT[j*16+ln16][quad*8]);
      bf16x8 xz = ld8bf(&WxT[(4+j)*16+ln16][quad*8]);
      bf16x8 xn = ld8bf(&WxT[(8+j)*16+ln16][quad*8]);
      f32x4 z4 = (f32x4){0.f,0.f,0.f,0.f};
      f32x4 ar = __builtin_amdgcn_mfma_f32_16x16x32_bf16(xr, axc, z4, 0,0,0);
      ar = __builtin_amdgcn_mfma_f32_16x16x32_bf16(whf[0][j], ah0, ar, 0,0,0);
      ar = __builtin_amdgcn_mfma_f32_16x16x32_bf16(whf[1][j], ah1, ar, 0,0,0);
      f32x4 az = __builtin_amdgcn_mfma_f32_16x16x32_bf16(xz, axc, z4, 0,0,0);
      az = __builtin_amdgcn_mfma_f32_16x16x32_bf16(whf[0][4+j], ah0, az, 0,0,0);
      az = __builtin_amdgcn_mfma_f32_16x16x32_bf16(whf[1][4+j], ah1, az, 0,0,0);
      f32x4 an = __builtin_amdgcn_mfma_f32_16x16x32_bf16(xn, axc, z4, 0,0,0);
      f32x4 ah = __builtin_amdgcn_mfma_f32_16x16x32_bf16(whf[0][8+j], ah0, bhn2[j], 0,0,0);
      ah = __builtin_amdgcn_mfma_f32_16x16x32_bf16(whf[1][8+j], ah1, ah, 0,0,0);
      f32x4 hv;
      #pragma unroll
      for (int i=0;i<4;++i){
        float Er = __expf(-ar[i]);
        float Ez = __expf(-az[i]);
        float pr = 1.f + Er, pz = 1.f + Ez;
        float D  = frcp(pr * pz);
        float r  = D * pz;
        float z  = D * pr;
        float nn = tanh_(an[i] + r * ah[i]);
        float h  = fmaf(z, hprev[j][i]-nn, nn);
        hprev[j][i] = h;
        vmax[j][i] = fmaxf(vmax[j][i], h);
        hv[i] = h;
      }
      *(uint2*)&hb[wave][ln16][j*16+quad*4] = make_uint2(pk2(hv[0],hv[1]), pk2(hv[2],hv[3]));
    }
    LDS_WAIT();
    axc = axn;
  }
  float* orow = rnn + (size_t)(rowbase + ln16)*64;
  #pragma unroll
  for (int j=0;j<4;++j)
    *(f32x4*)(orow + j*16 + quad*4) = vmax[j];
}

// ---------------------------------------------------------------------------
// 2-barrier scan: each wave serially scans a 640-elem segment (LDS-buffered).
// ---------------------------------------------------------------------------
__global__ __launch_bounds__(1024) void scan_kernel(const int* __restrict__ counts,
                                                    int* __restrict__ rowptr, int* __restrict__ cursor){
  __shared__ int incl[10240];
  __shared__ int wsum[16];
  int tid=threadIdx.x, wave=tid>>6, lane=tid&63;
  int base = wave*640;
  int carry=0;
  #pragma unroll
  for (int c=0;c<10;++c){
    int i = base + c*64 + lane;
    int v = (i<NN)? counts[i] : 0;
    int s = v;
    #pragma unroll
    for (int off=1;off<64;off<<=1){
      int t_ = __shfl_up(s, off);
      if (lane>=off) s += t_;
    }
    s += carry;
    incl[base + c*64 + lane] = s;
    carry = __shfl(s, 63);
  }
  if (lane==63) wsum[wave]=carry;
  __syncthreads();
  if (wave==0){
    int w_ = (lane<16)? wsum[lane]:0;
    #pragma unroll
    for (int off=1;off<16;off<<=1){
      int t_ = __shfl_up(w_, off);
      if (lane>=off) w_ += t_;
    }
    if (lane<16) wsum[lane]=w_;   // inclusive prefix of wave sums
  }
  __syncthreads();
  int woff = (wave>0)? wsum[wave-1] : 0;
  #pragma unroll
  for (int c=0;c<10;++c){
    int i = base + c*64 + lane;
    if (i<NN){
      int excl = incl[i] + woff - counts[i];
      rowptr[i]=excl; cursor[i]=excl;
    }
  }
  if (tid==0) rowptr[NN]=wsum[15];
}

// ---------------------------------------------------------------------------
// FUSED fill + EdgeNet-conv0 MLP: blocks 0-624 mlp2_e (rnn -> xinA),
// 625-1874 fill.
// ---------------------------------------------------------------------------
__global__ __launch_bounds__(256) void fill_mlp2e_kernel(
    const int* __restrict__ ei,
    const float* __restrict__ ea,
    int* __restrict__ cursor,
    int* __restrict__ ssrc,
    float* __restrict__ wcsr,
    const float* __restrict__ x,
    const int* __restrict__ ntid,
    const float* __restrict__ emb,
    const unsigned short* __restrict__ wt,  // prepped table (e0 at offset 0)
    const float* __restrict__ b1, const float* __restrict__ b2,
    unsigned short* __restrict__ out)
{
  if (blockIdx.x >= 625){
    int e = (blockIdx.x-625)*256 + threadIdx.x;
    int d = ei[NE+e];
    int pos = atomicAdd(&cursor[d],1);
    ssrc[pos]=ei[e];
    wcsr[pos]=ea[e];
    return;
  }
  mlp2_body(blockIdx.x, x, ntid, emb, wt, b1, wt + 6144, b2, out);
}

// ---------------------------------------------------------------------------
// FUSED aggregation + 2-layer MLP with XCD-partitioned batches and global
// bf16 weights. Quad-per-node gather. Grid 2504. (Plain variant: wcsr edge
// weights — EdgeNet conv0->conv1.)
// ---------------------------------------------------------------------------
__global__ __launch_bounds__(256) void aggr_mlp_kernel(
    const float* __restrict__ x,            // base [BN][64] f32
    const unsigned short* __restrict__ xin, // messages [BN][64] bf16
    const int* __restrict__ rowptr,
    const int* __restrict__ ssrc,
    const float* __restrict__ wp,           // p-indexed weights
    int bstride,
    const int* __restrict__ ntid,
    const float* __restrict__ emb,          // [3][16]
    const unsigned short* __restrict__ W1T, // [64][96] bf16 (prepped)
    const float* __restrict__ b1,
    const unsigned short* __restrict__ W2T, // [64][64] bf16 (prepped)
    const float* __restrict__ b2,
    float* __restrict__ xe_out,             // [BN][64] f32 (= x + aggr)
    unsigned short* __restrict__ out)       // [BN][64] bf16 (= MLP(..))
{
  int u = blockIdx.x;
  int b = (u & 7) >> 1;
  int m = ((u >> 3) << 1) | (u & 1);
  if (m >= 625) return;
  int row0 = b*NN + m*16;

  __shared__ __attribute__((aligned(16))) unsigned short hb[16][72];
  __shared__ __attribute__((aligned(16))) unsigned short h2[16][72];
  int tid = threadIdx.x;
  int wave = tid>>6, lane = tid&63, ln16 = lane&15, quad = lane>>4;
  int r = wave*4 + quad;                  // node slot 0..15
  int row = row0 + r;
  int n = m*16 + r;
  int l = ln16;
  int p0 = rowptr[n], p1 = rowptr[n+1];
  const unsigned short* xb_ = xin + (size_t)b*NN*64;
  const float* wb = wp + (size_t)b*bstride;
  float a0=0.f, a1=0.f, a2=0.f, a3=0.f;
  #pragma unroll 4
  for (int p=p0; p<p1; ++p){
    int s = ssrc[p];
    float w = wb[p];
    uint2 mm = *(const uint2*)(xb_ + (size_t)s*64 + l*4);
    a0 += bf2f((unsigned short)(mm.x & 0xffffu)) * w;
    a1 += bf2f((unsigned short)(mm.x >> 16)) * w;
    a2 += bf2f((unsigned short)(mm.y & 0xffffu)) * w;
    a3 += bf2f((unsigned short)(mm.y >> 16)) * w;
  }
  float4 base = *(const float4*)(x + (size_t)row*64 + l*4);
  float o0=base.x+a0, o1=base.y+a1, o2=base.z+a2, o3=base.w+a3;
  float4 ov; ov.x=o0; ov.y=o1; ov.z=o2; ov.w=o3;
  *(float4*)(xe_out + (size_t)row*64 + l*4) = ov;
  *(uint2*)&hb[r][l*4] = make_uint2(pk2(o0,o1), pk2(o2,o3));
  __syncthreads();

  // MLP phase: block-wide 16-row tile; wave w -> output tile w (16 dims)
  int id = ntid[m*16 + ln16];
  bf16x8 xa0 = ld8bf(&hb[ln16][quad*8]);
  bf16x8 xa1 = ld8bf(&hb[ln16][32+quad*8]);
  bf16x8 xa2 = (quad<2) ? ld8f(emb + id*16 + quad*8) : zero8();
  float bb = b1[wave*16+ln16];
  f32x4 acc = (f32x4){bb,bb,bb,bb};
  acc = __builtin_amdgcn_mfma_f32_16x16x32_bf16(xa0, ld8bf(W1T + (wave*16+ln16)*96 + quad*8),      acc, 0,0,0);
  acc = __builtin_amdgcn_mfma_f32_16x16x32_bf16(xa1, ld8bf(W1T + (wave*16+ln16)*96 + 32 + quad*8), acc, 0,0,0);
  acc = __builtin_amdgcn_mfma_f32_16x16x32_bf16(xa2, ld8bf(W1T + (wave*16+ln16)*96 + 64 + quad*8), acc, 0,0,0);
  #pragma unroll
  for (int i=0;i<4;++i)
    h2[quad*4+i][wave*16+ln16] = f2bf(lrelu(acc[i]));
  __syncthreads();
  bf16x8 hh0 = ld8bf(&h2[ln16][quad*8]);
  bf16x8 hh1 = ld8bf(&h2[ln16][32+quad*8]);
  float b2v = b2[wave*16+ln16];
  f32x4 acc2 = (f32x4){b2v,b2v,b2v,b2v};
  acc2 = __builtin_amdgcn_mfma_f32_16x16x32_bf16(hh0, ld8bf(W2T + (wave*16+ln16)*64 + quad*8),      acc2, 0,0,0);
  acc2 = __builtin_amdgcn_mfma_f32_16x16x32_bf16(hh1, ld8bf(W2T + (wave*16+ln16)*64 + 32 + quad*8), acc2, 0,0,0);
  #pragma unroll
  for (int i=0;i<4;++i)
    out[(size_t)(row0+quad*4+i)*64 + wave*16+ln16] = f2bf(lrelu(acc2[i]));
}

// ---------------------------------------------------------------------------
// R11: FUSED gated aggregation + 2-layer MLP. The edge gate is computed
// INLINE per edge: g = relu(W2·lrelu(u[s]+v[n]+b1)+b2) from uvp rows,
// gathered alongside the xin row (loads issue together -> latency overlap).
// No gat materialization. Grid 2504.
// ---------------------------------------------------------------------------
__global__ __launch_bounds__(256) void aggr_mlp_gate_kernel(
    const float* __restrict__ x,            // base (rnn) [BN][64] f32
    const unsigned short* __restrict__ xin, // messages [BN][64] bf16
    const int* __restrict__ rowptr,
    const int* __restrict__ ssrc,
    const unsigned short* __restrict__ uvp, // [BN][128] bf16 (u|v)
    const float* __restrict__ gb1,          // efm b1 [64]
    const float* __restrict__ gW2,          // efm W2 [64]
    const float* __restrict__ gb2,          // efm b2 [1]
    const int* __restrict__ ntid,
    const float* __restrict__ emb,          // [3][16]
    const unsigned short* __restrict__ W1T, // g1 set
    const float* __restrict__ b1,
    const unsigned short* __restrict__ W2T,
    const float* __restrict__ b2,
    float* __restrict__ xe_out,             // [BN][64] f32
    unsigned short* __restrict__ out)       // [BN][64] bf16
{
  int u = blockIdx.x;
  int b = (u & 7) >> 1;
  int m = ((u >> 3) << 1) | (u & 1);
  if (m >= 625) return;
  int row0 = b*NN + m*16;

  __shared__ __attribute__((aligned(16))) unsigned short hb[16][72];
  __shared__ __attribute__((aligned(16))) unsigned short h2[16][72];
  int tid = threadIdx.x;
  int wave = tid>>6, lane = tid&63, ln16 = lane&15, quad = lane>>4;
  int r = wave*4 + quad;                  // node slot 0..15
  int row = row0 + r;
  int n = m*16 + r;
  int l = ln16;
  int p0 = rowptr[n], p1 = rowptr[n+1];
  const unsigned short* xb_ = xin + (size_t)b*NN*64;
  const unsigned short* ub  = uvp + (size_t)b*NN*128;
  // node's v half + gate params (per-lane dims l*4..l*4+3)
  uint2 vv = *(const uint2*)(ub + (size_t)n*128 + 64 + l*4);
  float v0=bf2f((unsigned short)(vv.x&0xffffu)), v1=bf2f((unsigned short)(vv.x>>16));
  float v2=bf2f((unsigned short)(vv.y&0xffffu)), v3=bf2f((unsigned short)(vv.y>>16));
  float4 bb4 = *(const float4*)(gb1 + l*4);
  float4 ww4 = *(const float4*)(gW2 + l*4);
  float gb2v = gb2[0];
  float a0=0.f, a1=0.f, a2=0.f, a3=0.f;
  #pragma unroll 4
  for (int p=p0; p<p1; ++p){
    int s = ssrc[p];
    uint2 mm = *(const uint2*)(xb_ + (size_t)s*64 + l*4);
    uint2 uu = *(const uint2*)(ub  + (size_t)s*128 + l*4);
    float h0 = lrelu(bf2f((unsigned short)(uu.x&0xffffu)) + v0 + bb4.x);
    float h1 = lrelu(bf2f((unsigned short)(uu.x>>16))     + v1 + bb4.y);
    float h2_ = lrelu(bf2f((unsigned short)(uu.y&0xffffu)) + v2 + bb4.z);
    float h3 = lrelu(bf2f((unsigned short)(uu.y>>16))     + v3 + bb4.w);
    float part = h0*ww4.x + h1*ww4.y + h2_*ww4.z + h3*ww4.w;
    part += __shfl_xor(part,1);
    part += __shfl_xor(part,2);
    part += __shfl_xor(part,4);
    part += __shfl_xor(part,8);
    float g = part + gb2v;
    g = g>0.f ? g : 0.f;
    a0 += bf2f((unsigned short)(mm.x & 0xffffu)) * g;
    a1 += bf2f((unsigned short)(mm.x >> 16)) * g;
    a2 += bf2f((unsigned short)(mm.y & 0xffffu)) * g;
    a3 += bf2f((unsigned short)(mm.y >> 16)) * g;
  }
  float4 base = *(const float4*)(x + (size_t)row*64 + l*4);
  float o0=base.x+a0, o1=base.y+a1, o2=base.z+a2, o3=base.w+a3;
  float4 ov; ov.x=o0; ov.y=o1; ov.z=o2; ov.w=o3;
  *(float4*)(xe_out + (size_t)row*64 + l*4) = ov;
  *(uint2*)&hb[r][l*4] = make_uint2(pk2(o0,o1), pk2(o2,o3));
  __syncthreads();

  // MLP phase (g1)
  int id = ntid[m*16 + ln16];
  bf16x8 xa0 = ld8bf(&hb[ln16][quad*8]);
  bf16x8 xa1 = ld8bf(&hb[ln16][32+quad*8]);
  bf16x8 xa2 = (quad<2) ? ld8f(emb + id*16 + quad*8) : zero8();
  float bb = b1[wave*16+ln16];
  f32x4 acc = (f32x4){bb,bb,bb,bb};
  acc = __builtin_amdgcn_mfma_f32_16x16x32_bf16(xa0, ld8bf(W1T + (wave*16+ln16)*96 + quad*8),      acc, 0,0,0);
  acc = __builtin_amdgcn_mfma_f32_16x16x32_bf16(xa1, ld8bf(W1T + (wave*16+ln16)*96 + 32 + quad*8), acc, 0,0,0);
  acc = __builtin_amdgcn_mfma_f32_16x16x32_bf16(xa2, ld8bf(W1T + (wave*16+ln16)*96 + 64 + quad*8), acc, 0,0,0);
  #pragma unroll
  for (int i=0;i<4;++i)
    h2[quad*4+i][wave*16+ln16] = f2bf(lrelu(acc[i]));
  __syncthreads();
  bf16x8 hh0 = ld8bf(&h2[ln16][quad*8]);
  bf16x8 hh1 = ld8bf(&h2[ln16][32+quad*8]);
  float b2v = b2[wave*16+ln16];
  f32x4 acc2 = (f32x4){b2v,b2v,b2v,b2v};
  acc2 = __builtin_amdgcn_mfma_f32_16x16x32_bf16(hh0, ld8bf(W2T + (wave*16+ln16)*64 + quad*8),      acc2, 0,0,0);
  acc2 = __builtin_amdgcn_mfma_f32_16x16x32_bf16(hh1, ld8bf(W2T + (wave*16+ln16)*64 + 32 + quad*8), acc2, 0,0,0);
  #pragma unroll
  for (int i=0;i<4;++i)
    out[(size_t)(row0+quad*4+i)*64 + wave*16+ln16] = f2bf(lrelu(acc2[i]));
}

// ---------------------------------------------------------------------------
// FUSED aggregation + uv projection, XCD-partitioned, global bf16 uv weights
// + co-scheduled main-conv0 MLP (blocks 2504..3128: rnn -> xinA with g0 set;
// safe: aggr_mlp#1 has finished reading xinA). Grid 3129.
// ---------------------------------------------------------------------------
__global__ __launch_bounds__(256) void aggr_uv_mlp2g_kernel(
    const float* __restrict__ x,            // base [BN][64] f32
    const unsigned short* __restrict__ xin, // messages [BN][64] bf16
    const int* __restrict__ rowptr,
    const int* __restrict__ ssrc,
    const float* __restrict__ wp,           // wcsr (bstride 0)
    int bstride,
    const unsigned short* __restrict__ WT,  // [128][64] bf16 (prepped)
    unsigned short* __restrict__ uvp,       // [BN][128] bf16
    const float* __restrict__ rnn,          // mlp2_g input
    const int* __restrict__ ntid,
    const float* __restrict__ gemb,
    const unsigned short* __restrict__ wtg, // g0 set
    const float* __restrict__ gc0b1, const float* __restrict__ gc0b2,
    unsigned short* __restrict__ xinA)      // mlp2_g output
{
  int u = blockIdx.x;
  if (u >= 2504){
    mlp2_body(u - 2504, rnn, ntid, gemb, wtg, gc0b1, wtg + 6144, gc0b2, xinA);
    return;
  }
  int b = (u & 7) >> 1;
  int m = ((u >> 3) << 1) | (u & 1);
  if (m >= 625) return;
  int row0 = b*NN + m*16;

  __shared__ __attribute__((aligned(16))) unsigned short hbu[16][72];
  int tid = threadIdx.x;
  int wave = tid>>6, lane = tid&63, ln16 = lane&15, quad = lane>>4;
  int r = wave*4 + quad;
  int row = row0 + r;
  int n = m*16 + r;
  int l = ln16;
  int p0 = rowptr[n], p1 = rowptr[n+1];
  const unsigned short* xb_ = xin + (size_t)b*NN*64;
  const float* wb = wp + (size_t)b*bstride;
  float a0=0.f, a1=0.f, a2=0.f, a3=0.f;
  #pragma unroll 4
  for (int p=p0; p<p1; ++p){
    int s = ssrc[p];
    float w = wb[p];
    uint2 mm = *(const uint2*)(xb_ + (size_t)s*64 + l*4);
    a0 += bf2f((unsigned short)(mm.x & 0xffffu)) * w;
    a1 += bf2f((unsigned short)(mm.x >> 16)) * w;
    a2 += bf2f((unsigned short)(mm.y & 0xffffu)) * w;
    a3 += bf2f((unsigned short)(mm.y >> 16)) * w;
  }
  float4 base = *(const float4*)(x + (size_t)row*64 + l*4);
  float o0=base.x+a0, o1=base.y+a1, o2=base.z+a2, o3=base.w+a3;
  *(uint2*)&hbu[r][l*4] = make_uint2(pk2(o0,o1), pk2(o2,o3));
  __syncthreads();

  bf16x8 xa0 = ld8bf(&hbu[ln16][quad*8]);
  bf16x8 xa1 = ld8bf(&hbu[ln16][32+quad*8]);
  #pragma unroll
  for (int t=0;t<2;++t){
    int nt = wave*2 + t;   // output tile 0..7
    f32x4 acc = (f32x4){0.f,0.f,0.f,0.f};
    acc = __builtin_amdgcn_mfma_f32_16x16x32_bf16(xa0, ld8bf(WT + (nt*16+ln16)*64 + quad*8),      acc, 0,0,0);
    acc = __builtin_amdgcn_mfma_f32_16x16x32_bf16(xa1, ld8bf(WT + (nt*16+ln16)*64 + 32 + quad*8), acc, 0,0,0);
    #pragma unroll
    for (int i=0;i<4;++i)
      uvp[(size_t)(row0+quad*4+i)*128 + nt*16+ln16] = f2bf(acc[i]);
  }
}

// ---------------------------------------------------------------------------
// R11: Last aggregation fused with both FC heads + INLINE gate (recomputed
// from uvp, bit-identical to pass 6's). XCD-partitioned. Grid 10008.
// ---------------------------------------------------------------------------
__global__ __launch_bounds__(256) void aggr_final_kernel(
    const float* x,                        // [BN][64] f32 (xg input)
    const unsigned short* __restrict__ xin,// [BN][64] bf16
    const int* __restrict__ rowptr,
    const int* __restrict__ ssrc,
    const unsigned short* __restrict__ uvp,// [BN][128] bf16
    const float* __restrict__ gb1,         // efm b1
    const float* __restrict__ gW2,         // efm W2
    const float* __restrict__ gb2,         // efm b2
    const float* __restrict__ rnn,         // [BN][64]
    const float* __restrict__ Wr, const float* __restrict__ br,
    const float* __restrict__ Wg, const float* __restrict__ bg,
    float* __restrict__ out)               // [BN][7]
{
  int u = blockIdx.x;
  int b = (u & 7) >> 1;
  int m = ((u >> 3) << 1) | (u & 1);
  if (m >= 2500) return;

  __shared__ float sWr[448], sWg[448], sb[7];
  int tid=threadIdx.x;
  for (int i=tid;i<448;i+=256){ sWr[i]=Wr[i]; sWg[i]=Wg[i]; }
  if (tid<7) sb[tid]=br[tid]+bg[tid];
  __syncthreads();
  int wave=tid>>6, lane=tid&63;
  int sub=lane>>4, l=lane&15;
  int n = m*4 + wave;
  int bid = b*NN + n;
  int p0 = rowptr[n], p1 = rowptr[n+1];
  const unsigned short* xb_ = xin + (size_t)b*NN*64;
  const unsigned short* ub  = uvp + (size_t)b*NN*128;
  uint2 vv = *(const uint2*)(ub + (size_t)n*128 + 64 + l*4);
  float v0=bf2f((unsigned short)(vv.x&0xffffu)), v1=bf2f((unsigned short)(vv.x>>16));
  float v2=bf2f((unsigned short)(vv.y&0xffffu)), v3=bf2f((unsigned short)(vv.y>>16));
  float4 bb4 = *(const float4*)(gb1 + l*4);
  float4 ww4 = *(const float4*)(gW2 + l*4);
  float gb2v = gb2[0];
  float a0=0.f, a1=0.f, a2=0.f, a3=0.f;
  #pragma unroll 4
  for (int p=p0+sub; p<p1; p+=4){
    int s = ssrc[p];
    uint2 mm = *(const uint2*)(xb_ + (size_t)s*64 + l*4);
    uint2 uu = *(const uint2*)(ub  + (size_t)s*128 + l*4);
    float h0 = lrelu(bf2f((unsigned short)(uu.x&0xffffu)) + v0 + bb4.x);
    float h1 = lrelu(bf2f((unsigned short)(uu.x>>16))     + v1 + bb4.y);
    float h2 = lrelu(bf2f((unsigned short)(uu.y&0xffffu)) + v2 + bb4.z);
    float h3 = lrelu(bf2f((unsigned short)(uu.y>>16))     + v3 + bb4.w);
    float part = h0*ww4.x + h1*ww4.y + h2*ww4.z + h3*ww4.w;
    part += __shfl_xor(part,1);
    part += __shfl_xor(part,2);
    part += __shfl_xor(part,4);
    part += __shfl_xor(part,8);
    float g = part + gb2v;
    g = g>0.f ? g : 0.f;
    a0 += bf2f((unsigned short)(mm.x & 0xffffu)) * g;
    a1 += bf2f((unsigned short)(mm.x >> 16)) * g;
    a2 += bf2f((unsigned short)(mm.y & 0xffffu)) * g;
    a3 += bf2f((unsigned short)(mm.y >> 16)) * g;
  }
  a0 += __shfl_xor(a0,16); a0 += __shfl_xor(a0,32);
  a1 += __shfl_xor(a1,16); a1 += __shfl_xor(a1,32);
  a2 += __shfl_xor(a2,16); a2 += __shfl_xor(a2,32);
  a3 += __shfl_xor(a3,16); a3 += __shfl_xor(a3,32);
  if (sub==0){
    float4 base = *(const float4*)(x + (size_t)bid*64 + l*4);
    float o0=base.x+a0, o1=base.y+a1, o2=base.z+a2, o3=base.w+a3;
    float4 rr = *(const float4*)(rnn + (size_t)bid*64 + l*4);
    float part[7];
    #pragma unroll
    for (int q=0;q<7;++q)
      part[q] = o0*sWg[(l*4+0)*7+q] + o1*sWg[(l*4+1)*7+q]
              + o2*sWg[(l*4+2)*7+q] + o3*sWg[(l*4+3)*7+q]
              + rr.x*sWr[(l*4+0)*7+q] + rr.y*sWr[(l*4+1)*7+q]
              + rr.z*sWr[(l*4+2)*7+q] + rr.w*sWr[(l*4+3)*7+q];
    #pragma unroll
    for (int q=0;q<7;++q){
      part[q] += __shfl_xor(part[q],1);
      part[q] += __shfl_xor(part[q],2);
      part[q] += __shfl_xor(part[q],4);
      part[q] += __shfl_xor(part[q],8);
    }
    if (l==0){
      #pragma unroll
      for (int q=0;q<7;++q) out[(size_t)bid*7+q] = part[q] + sb[q];
    }
  }
}

// ---------------------------------------------------------------------------
extern "C" void kernel_launch(void* const* d_in, const int* in_sizes, int n_in,
                              void* d_out, int out_size, void* d_ws, size_t ws_size,
                              hipStream_t stream)
{
  (void)in_sizes; (void)n_in; (void)out_size; (void)ws_size;
  const float* input_day = (const float*)d_in[0];
  const int* ei    = (const int*)d_in[1];
  const int* ntid  = (const int*)d_in[2];
  const float* edge_attr = (const float*)d_in[3];
  const float* gWx = (const float*)d_in[4];
  const float* gWh = (const float*)d_in[5];
  const float* gbx = (const float*)d_in[6];
  const float* gbh = (const float*)d_in[7];
  const float* rW  = (const float*)d_in[8];
  const float* rb  = (const float*)d_in[9];
  const float* eemb= (const float*)d_in[10];
  const float* gemb= (const float*)d_in[11];
  const float* ec0W1=(const float*)d_in[12];
  const float* ec0b1=(const float*)d_in[13];
  const float* ec0W2=(const float*)d_in[14];
  const float* ec0b2=(const float*)d_in[15];
  const float* ec1W1=(const float*)d_in[16];
  const float* ec1b1=(const float*)d_in[17];
  const float* ec1W2=(const float*)d_in[18];
  const float* ec1b2=(const float*)d_in[19];
  const float* gc0W1=(const float*)d_in[20];
  const float* gc0b1=(const float*)d_in[21];
  const float* gc0W2=(const float*)d_in[22];
  const float* gc0b2=(const float*)d_in[23];
  const float* gc1W1=(const float*)d_in[24];
  const float* gc1b1=(const float*)d_in[25];
  const float* gc1W2=(const float*)d_in[26];
  const float* gc1b2=(const float*)d_in[27];
  const float* efmW1=(const float*)d_in[28];
  const float* efmb1=(const float*)d_in[29];
  const float* efmW2=(const float*)d_in[30];
  const float* efmb2=(const float*)d_in[31];
  const float* gcnW =(const float*)d_in[32];
  const float* gcnb =(const float*)d_in[33];

  // Workspace layout — ~43.6 MB (known-good envelope), with region reuse:
  //   gat region: xinB (EdgeNet conv1 messages, passes 4-5) then xinD
  //     (main conv1 messages, passes 6-7). No gate storage (R11: inline).
  //   uvp: written pass 5, read passes 6+7 (inline gate) — never aliased.
  //   Prepped bf16 weight tables (96KB) in d_out; overwritten by aggr_final.
  char* ws = (char*)d_ws;
  float*          rnn = (float*)(ws);                      // 10,240,000 B
  float*          xe  = (float*)(ws + 10240000);           // 10,240,000 B
  unsigned short* xinA= (unsigned short*)(ws + 20480000);  //  5,120,000 B
  unsigned short* uvp = (unsigned short*)(ws + 25600000);  // 10,240,000 B
  float*          gat = (float*)(ws + 35840000);           //  5,120,000 B (reuse)
  int* rowptr= (int*)(ws + 40960000);                      //     40,004 B
  int* cursor= (int*)(ws + 41000064);                      //     40,000 B
  int* counts= (int*)(ws + 41040064);                      //     40,000 B
  int*   ssrc= (int*)(ws + 41080064);                      //  1,280,000 B
  float* wcsr= (float*)(ws + 42360064);                    //  1,280,000 B -> 43,640,064
  unsigned short* xinB = (unsigned short*)gat;             // passes 4-5
  unsigned short* xinD = (unsigned short*)gat;             // passes 6-7 (xinB dead)
  unsigned short* wt   = (unsigned short*)d_out;           // prepped weights (96KB scratch)

  // CSR build + GRU + weight-prep, horizontally fused
  hipMemsetAsync(counts, 0, NN*sizeof(int), stream);
  // gru (0-624) || count (625-1874) || weight-prep (1875-1882)
  gru_count_kernel<<<1883, 256, 0, stream>>>(input_day, gWx, gWh, gbx, gbh, rnn,
                                             ei, counts,
                                             ec0W1, ec0W2, ec1W1, ec1W2,
                                             gc0W1, gc0W2, gc1W1, gc1W2,
                                             efmW1, wt);
  scan_kernel<<<1, 1024, 0, stream>>>(counts, rowptr, cursor);
  // mlp2_e (0-624, rnn->xinA, e0 weights) || fill (625-1874)
  fill_mlp2e_kernel<<<1875, 256, 0, stream>>>(ei, edge_attr, cursor, ssrc, wcsr,
                                              rnn, ntid, eemb,
                                              wt, ec0b1, ec0b2, xinA);
  // EdgeNet: conv0 aggregation fused with conv1 MLP (e1 weights) -> xe1 + xin_B
  aggr_mlp_kernel<<<2504, 256, 0, stream>>>(rnn, xinA, rowptr, ssrc, wcsr, 0,
                                            ntid, eemb,
                                            wt + WT_SET, ec1b1, wt + WT_SET + 6144, ec1b2,
                                            xe, xinB);
  // EdgeNet conv1 aggregation + uv projection || mlp2_g (g0, rnn->xinA)
  aggr_uv_mlp2g_kernel<<<3129, 256, 0, stream>>>(xe, xinB, rowptr, ssrc, wcsr, 0,
                                                 wt + WT_UV, uvp,
                                                 rnn, ntid, gemb,
                                                 wt + 2*WT_SET, gc0b1, gc0b2, xinA);
  // Main conv0 aggregation with INLINE gate, fused with conv1 MLP (g1)
  aggr_mlp_gate_kernel<<<2504, 256, 0, stream>>>(rnn, xinA, rowptr, ssrc,
                                                 uvp, efmb1, efmW2, efmb2,
                                                 ntid, gemb,
                                                 wt + 3*WT_SET, gc1b1, wt + 3*WT_SET + 6144, gc1b2,
                                                 xe, xinD);
  // last aggregation (inline gate) fused with both FC heads -> d_out
  aggr_final_kernel<<<10008, 256, 0, stream>>>(xe, xinD, rowptr, ssrc,
                                               uvp, efmb1, efmW2, efmb2, rnn,
                                               rW, rb, gcnW, gcnb, (float*)d_out);
}

// Round 13
// 419.123 us; speedup vs baseline: 1.0279x; 1.0279x over previous
//
#include <hip/hip_runtime.h>
#include <hip/hip_bf16.h>

// Dims
#define NB 4
#define NN 10000
#define NE 320000
#define BN 40000   // NB*NN
#define NL 7

typedef float f32x4 __attribute__((ext_vector_type(4)));
typedef __bf16 bf16x8 __attribute__((ext_vector_type(8)));

__device__ __forceinline__ float bf2f(unsigned short u){
  unsigned x = ((unsigned)u) << 16;
  return __builtin_bit_cast(float, x);
}
__device__ __forceinline__ unsigned short f2bf(float f){
  unsigned u = __builtin_bit_cast(unsigned, f);
  u += 0x7fffu + ((u >> 16) & 1u);
  return (unsigned short)(u >> 16);
}
__device__ __forceinline__ bf16x8 zero8(){
  uint4 z = make_uint4(0u,0u,0u,0u);
  return __builtin_bit_cast(bf16x8, z);
}
__device__ __forceinline__ bf16x8 one8(){
  // bf16 1.0 in element 0 (k=16 constant-1 bias channel), rest zero
  uint4 z = make_uint4(0x3f80u,0u,0u,0u);
  return __builtin_bit_cast(bf16x8, z);
}
__device__ __forceinline__ bf16x8 ld8bf(const unsigned short* p){
  uint4 u = *(const uint4*)p;
  return __builtin_bit_cast(bf16x8, u);
}
// packed RNE f32->bf16 pair: 1 instr instead of ~8 integer ops
__device__ __forceinline__ unsigned pk2(float lo, float hi){
  unsigned r;
  asm("v_cvt_pk_bf16_f32 %0, %1, %2" : "=v"(r) : "v"(lo), "v"(hi));
  return r;
}
__device__ __forceinline__ bf16x8 ld8f(const float* p){
  float4 a = *(const float4*)p;
  float4 b = *(const float4*)(p+4);
  uint4 u = make_uint4(pk2(a.x,a.y), pk2(a.z,a.w), pk2(b.x,b.y), pk2(b.z,b.w));
  return __builtin_bit_cast(bf16x8, u);
}
__device__ __forceinline__ float frcp(float x){ return __builtin_amdgcn_rcpf(x); }
__device__ __forceinline__ float tanh_(float x){ return 1.f - 2.f*frcp(__expf(2.f*x)+1.f); }
__device__ __forceinline__ float lrelu(float x){ return x > 0.f ? x : 0.01f*x; }

#define LDS_WAIT() asm volatile("s_waitcnt lgkmcnt(0)" ::: "memory")

// Prepped bf16 weight-table offsets (in d_out scratch, overwritten at the end
// by aggr_final — weights are dead by then). Layout per conv set:
//   W1T[64][96] (6144) + W2T[64][64] (4096) = 10240 elems.
// Sets: e0, e1, g0, g1, then uv WT[128][64] (8192). Total 49152 elems = 96KB.
#define WT_SET   10240
#define WT_UV    40960
#define WT_TOTAL 49152

// ---------------------------------------------------------------------------
// Fused 2-layer GCN MLP body (device fn). Weights read as bf16 fragments
// DIRECTLY from the prepped global table (L2-hot) — no staging, no barrier.
// LDS = hb only (9216B).
// ---------------------------------------------------------------------------
__device__ __forceinline__ void mlp2_body(
    int bid,
    const float* __restrict__ x,            // [BN][64] f32
    const int* __restrict__ ntid,           // [NN]
    const float* __restrict__ emb,          // [3][16]
    const unsigned short* __restrict__ W1T, // [64][96] bf16 (prepped)
    const float* __restrict__ b1,           // [64]
    const unsigned short* __restrict__ W2T, // [64][64] bf16 (prepped)
    const float* __restrict__ b2,           // [64]
    unsigned short* __restrict__ out)       // [BN][64] bf16
{
  __shared__ __attribute__((aligned(16))) unsigned short hb[4][16][72];
  int tid = threadIdx.x;
  int wave = tid>>6, lane = tid&63, ln16 = lane&15, quad = lane>>4;
  int row0 = bid*64 + wave*16;
  int r_ = row0 + ln16;
  const float* xr = x + (size_t)r_*64;
  bf16x8 a0 = ld8f(xr + quad*8);
  bf16x8 a1 = ld8f(xr + 32 + quad*8);
  int id = ntid[r_ % NN];
  bf16x8 a2 = (quad<2) ? ld8f(emb + id*16 + quad*8) : zero8();

  f32x4 acc[4];
  #pragma unroll
  for (int nt=0;nt<4;++nt){
    float bb = b1[nt*16+ln16];
    acc[nt] = (f32x4){bb,bb,bb,bb};
    acc[nt] = __builtin_amdgcn_mfma_f32_16x16x32_bf16(a0, ld8bf(W1T + (nt*16+ln16)*96 + quad*8),      acc[nt], 0,0,0);
    acc[nt] = __builtin_amdgcn_mfma_f32_16x16x32_bf16(a1, ld8bf(W1T + (nt*16+ln16)*96 + 32 + quad*8), acc[nt], 0,0,0);
    acc[nt] = __builtin_amdgcn_mfma_f32_16x16x32_bf16(a2, ld8bf(W1T + (nt*16+ln16)*96 + 64 + quad*8), acc[nt], 0,0,0);
  }
  #pragma unroll
  for (int nt=0;nt<4;++nt)
    #pragma unroll
    for (int i=0;i<4;++i)
      hb[wave][quad*4+i][nt*16+ln16] = f2bf(lrelu(acc[nt][i]));
  LDS_WAIT();
  bf16x8 h0 = ld8bf(&hb[wave][ln16][quad*8]);
  bf16x8 h1 = ld8bf(&hb[wave][ln16][32+quad*8]);
  f32x4 acc2[4];
  #pragma unroll
  for (int nt=0;nt<4;++nt){
    float bb = b2[nt*16+ln16];
    acc2[nt] = (f32x4){bb,bb,bb,bb};
    acc2[nt] = __builtin_amdgcn_mfma_f32_16x16x32_bf16(h0, ld8bf(W2T + (nt*16+ln16)*64 + quad*8),      acc2[nt], 0,0,0);
    acc2[nt] = __builtin_amdgcn_mfma_f32_16x16x32_bf16(h1, ld8bf(W2T + (nt*16+ln16)*64 + 32 + quad*8), acc2[nt], 0,0,0);
  }
  #pragma unroll
  for (int nt=0;nt<4;++nt)
    #pragma unroll
    for (int i=0;i<4;++i)
      out[(size_t)(row0+quad*4+i)*64 + nt*16+ln16] = f2bf(lrelu(acc2[nt][i]));
}

// ---------------------------------------------------------------------------
// GRU (R5 structure — measured latency floor ~76-81us, grid-limited)
// FUSED with count (blocks 625-1874) and weight-prep (blocks 1875-1882).
// DEAD ENDS: Wx-frag hoist spill (107us); 320-thr blocks (95us); pure-reg
// h recurrence (78-81us); (256,3) scratch spill (147us); WxT stride 32
// 8-way conflicts; R7 pass-based fused gather (+26us); R11 inline gate
// (+11.5us).
// ---------------------------------------------------------------------------
__global__ __launch_bounds__(256, 2) void gru_count_kernel(
    const float* __restrict__ xd,   // [BN][256] f32 (T*DIN)
    const float* __restrict__ Wx,   // [16][192]
    const float* __restrict__ Wh,   // [64][192]
    const float* __restrict__ bx,   // [192]
    const float* __restrict__ bh,   // [192]
    float* __restrict__ rnn,        // [BN][64] f32 (max over T)
    const int* __restrict__ ei,
    int* __restrict__ counts,
    const float* __restrict__ ec0W1, const float* __restrict__ ec0W2,
    const float* __restrict__ ec1W1, const float* __restrict__ ec1W2,
    const float* __restrict__ gc0W1, const float* __restrict__ gc0W2,
    const float* __restrict__ gc1W1, const float* __restrict__ gc1W2,
    const float* __restrict__ efmW1,
    unsigned short* __restrict__ wt)
{
  if (blockIdx.x >= 1875){
    // weight prep: 8 blocks x 256 thr
    int pidx = blockIdx.x - 1875;
    for (int i = pidx*256 + threadIdx.x; i < WT_TOTAL; i += 2048){
      unsigned short v;
      if (i < WT_UV){
        int s = i / WT_SET, j = i - s*WT_SET;
        const float* W1s = (s==0) ? ec0W1 : (s==1) ? ec1W1 : (s==2) ? gc0W1 : gc1W1;
        const float* W2s = (s==0) ? ec0W2 : (s==1) ? ec1W2 : (s==2) ? gc0W2 : gc1W2;
        if (j < 6144){
          int n = j / 96, k = j - n*96;
          v = (k < 80) ? f2bf(W1s[k*64+n]) : (unsigned short)0;
        } else {
          int j2 = j - 6144;
          int n = j2 >> 6, k = j2 & 63;
          v = f2bf(W2s[k*64+n]);
        }
      } else {
        int j = i - WT_UV;
        int n = j >> 6, k = j & 63;
        v = f2bf((n < 64) ? efmW1[k*64+n] : efmW1[4096 + k*64 + (n-64)]);
      }
      wt[i] = v;
    }
    return;
  }
  if (blockIdx.x >= 625){
    int e = (blockIdx.x-625)*256 + threadIdx.x;
    atomicAdd(&counts[ei[NE+e]], 1);
    return;
  }
  __shared__ __attribute__((aligned(16))) unsigned short WhT[192][72];
  __shared__ __attribute__((aligned(16))) unsigned short WxT[192][40]; // k16=bias, k17..32 zero
  __shared__ __attribute__((aligned(16))) unsigned short hb[4][16][76]; // [row r][hdim], padded
  int tid = threadIdx.x;
  int wave = tid >> 6, lane = tid & 63;
  int ln16 = lane & 15, quad = lane >> 4;

  for (int i = tid; i < 64*192; i += 256){
    int k = i / 192, n = i - k*192;
    WhT[n][k] = f2bf(Wh[i]);
  }
  for (int i = tid; i < 16*192; i += 256){
    int k = i / 192, n = i - k*192;
    WxT[n][k] = f2bf(Wx[i]);
    WxT[n][17+k] = 0;                 // zero k17..32 (k24..31 read by quad 3)
  }
  if (tid < 192){
    // bias channel: r/z gates get bx+bh, n-gate x-part gets bx only
    float bias = (tid < 128) ? (bx[tid] + bh[tid]) : bx[tid];
    WxT[tid][16] = f2bf(bias);
  }
  for (int i = tid; i < 4*16*76; i += 256) ((unsigned short*)hb)[i] = 0;
  __syncthreads();   // the only block barrier

  int rowbase = blockIdx.x * 64 + wave * 16;

  bf16x8 whf[2][12];
  #pragma unroll
  for (int kt=0; kt<2; ++kt)
    #pragma unroll
    for (int nt=0; nt<12; ++nt)
      whf[kt][nt] = ld8bf(&WhT[nt*16 + ln16][kt*32 + quad*8]);

  f32x4 bhn2[4];
  #pragma unroll
  for (int j=0;j<4;++j)
    bhn2[j] = *(const f32x4*)(bh + 128 + j*16 + quad*4);

  f32x4 hprev[4], vmax[4];
  #pragma unroll
  for (int j=0;j<4;++j){
    hprev[j] = (f32x4){0.f,0.f,0.f,0.f};
    vmax[j]  = (f32x4){-1e30f,-1e30f,-1e30f,-1e30f};
  }

  const float* xrow = xd + (size_t)(rowbase + ln16) * 256;
  unsigned short* hrow = &hb[wave][ln16][0];

  bf16x8 axc;
  if (quad < 2) axc = ld8f(xrow + quad*8);
  else          axc = (quad == 2) ? one8() : zero8();

  for (int t = 0; t < 16; ++t){
    bf16x8 axn;
    if (quad < 2) axn = (t < 15) ? ld8f(xrow + (t+1)*16 + quad*8) : zero8();
    else          axn = (quad == 2) ? one8() : zero8();
    bf16x8 ah0 = ld8bf(hrow + quad*8);        // B frag: h[r=ln16][k=quad*8+e]
    bf16x8 ah1 = ld8bf(hrow + 32 + quad*8);

    #pragma unroll
    for (int j=0;j<4;++j){
      bf16x8 xr = ld8bf(&WxT[j*16+ln16][quad*8]);
      bf16x8 xz = ld8bf(&WxT[(4+j)*16+ln16][quad*8]);
      bf16x8 xn = ld8bf(&WxT[(8+j)*16+ln16][quad*8]);
      f32x4 z4 = (f32x4){0.f,0.f,0.f,0.f};
      f32x4 ar = __builtin_amdgcn_mfma_f32_16x16x32_bf16(xr, axc, z4, 0,0,0);
      ar = __builtin_amdgcn_mfma_f32_16x16x32_bf16(whf[0][j], ah0, ar, 0,0,0);
      ar = __builtin_amdgcn_mfma_f32_16x16x32_bf16(whf[1][j], ah1, ar, 0,0,0);
      f32x4 az = __builtin_amdgcn_mfma_f32_16x16x32_bf16(xz, axc, z4, 0,0,0);
      az = __builtin_amdgcn_mfma_f32_16x16x32_bf16(whf[0][4+j], ah0, az, 0,0,0);
      az = __builtin_amdgcn_mfma_f32_16x16x32_bf16(whf[1][4+j], ah1, az, 0,0,0);
      f32x4 an = __builtin_amdgcn_mfma_f32_16x16x32_bf16(xn, axc, z4, 0,0,0);
      f32x4 ah = __builtin_amdgcn_mfma_f32_16x16x32_bf16(whf[0][8+j], ah0, bhn2[j], 0,0,0);
      ah = __builtin_amdgcn_mfma_f32_16x16x32_bf16(whf[1][8+j], ah1, ah, 0,0,0);
      f32x4 hv;
      #pragma unroll
      for (int i=0;i<4;++i){
        float Er = __expf(-ar[i]);
        float Ez = __expf(-az[i]);
        float pr = 1.f + Er, pz = 1.f + Ez;
        float D  = frcp(pr * pz);
        float r  = D * pz;
        float z  = D * pr;
        float nn = tanh_(an[i] + r * ah[i]);
        float h  = fmaf(z, hprev[j][i]-nn, nn);
        hprev[j][i] = h;
        vmax[j][i] = fmaxf(vmax[j][i], h);
        hv[i] = h;
      }
      *(uint2*)&hb[wave][ln16][j*16+quad*4] = make_uint2(pk2(hv[0],hv[1]), pk2(hv[2],hv[3]));
    }
    LDS_WAIT();
    axc = axn;
  }
  float* orow = rnn + (size_t)(rowbase + ln16)*64;
  #pragma unroll
  for (int j=0;j<4;++j)
    *(f32x4*)(orow + j*16 + quad*4) = vmax[j];
}

// ---------------------------------------------------------------------------
// 2-barrier scan: each wave serially scans a 640-elem segment (LDS-buffered).
// ---------------------------------------------------------------------------
__global__ __launch_bounds__(1024) void scan_kernel(const int* __restrict__ counts,
                                                    int* __restrict__ rowptr, int* __restrict__ cursor){
  __shared__ int incl[10240];
  __shared__ int wsum[16];
  int tid=threadIdx.x, wave=tid>>6, lane=tid&63;
  int base = wave*640;
  int carry=0;
  #pragma unroll
  for (int c=0;c<10;++c){
    int i = base + c*64 + lane;
    int v = (i<NN)? counts[i] : 0;
    int s = v;
    #pragma unroll
    for (int off=1;off<64;off<<=1){
      int t_ = __shfl_up(s, off);
      if (lane>=off) s += t_;
    }
    s += carry;
    incl[base + c*64 + lane] = s;
    carry = __shfl(s, 63);
  }
  if (lane==63) wsum[wave]=carry;
  __syncthreads();
  if (wave==0){
    int w_ = (lane<16)? wsum[lane]:0;
    #pragma unroll
    for (int off=1;off<16;off<<=1){
      int t_ = __shfl_up(w_, off);
      if (lane>=off) w_ += t_;
    }
    if (lane<16) wsum[lane]=w_;   // inclusive prefix of wave sums
  }
  __syncthreads();
  int woff = (wave>0)? wsum[wave-1] : 0;
  #pragma unroll
  for (int c=0;c<10;++c){
    int i = base + c*64 + lane;
    if (i<NN){
      int excl = incl[i] + woff - counts[i];
      rowptr[i]=excl; cursor[i]=excl;
    }
  }
  if (tid==0) rowptr[NN]=wsum[15];
}

// ---------------------------------------------------------------------------
// FUSED fill + EdgeNet-conv0 MLP: blocks 0-624 mlp2_e (rnn -> xinA),
// 625-1874 fill. LDS 9216B (hb only) -> 8 blocks/CU.
// ---------------------------------------------------------------------------
__global__ __launch_bounds__(256) void fill_mlp2e_kernel(
    const int* __restrict__ ei,
    const float* __restrict__ ea,
    int* __restrict__ cursor,
    int* __restrict__ ssrc,
    float* __restrict__ wcsr,
    const float* __restrict__ x,
    const int* __restrict__ ntid,
    const float* __restrict__ emb,
    const unsigned short* __restrict__ wt,  // prepped table (e0 at offset 0)
    const float* __restrict__ b1, const float* __restrict__ b2,
    unsigned short* __restrict__ out)
{
  if (blockIdx.x >= 625){
    int e = (blockIdx.x-625)*256 + threadIdx.x;
    int d = ei[NE+e];
    int pos = atomicAdd(&cursor[d],1);
    ssrc[pos]=ei[e];
    wcsr[pos]=ea[e];
    return;
  }
  mlp2_body(blockIdx.x, x, ntid, emb, wt, b1, wt + 6144, b2, out);
}

// ---------------------------------------------------------------------------
// FUSED aggregation + 2-layer MLP with R9 XCD-partitioned batches and R10
// global bf16 weights (LDS 4608B -> 8 blocks/CU). Quad-per-node gather
// (R6 body, measured best). Grid 2504.
// ---------------------------------------------------------------------------
__global__ __launch_bounds__(256) void aggr_mlp_kernel(
    const float* __restrict__ x,            // base [BN][64] f32
    const unsigned short* __restrict__ xin, // messages [BN][64] bf16
    const int* __restrict__ rowptr,
    const int* __restrict__ ssrc,
    const float* __restrict__ wp,           // p-indexed weights
    int bstride,
    const int* __restrict__ ntid,
    const float* __restrict__ emb,          // [3][16]
    const unsigned short* __restrict__ W1T, // [64][96] bf16 (prepped)
    const float* __restrict__ b1,
    const unsigned short* __restrict__ W2T, // [64][64] bf16 (prepped)
    const float* __restrict__ b2,
    float* __restrict__ xe_out,             // [BN][64] f32 (= x + aggr)
    unsigned short* __restrict__ out)       // [BN][64] bf16 (= MLP(..))
{
  int u = blockIdx.x;
  int b = (u & 7) >> 1;
  int m = ((u >> 3) << 1) | (u & 1);
  if (m >= 625) return;
  int row0 = b*NN + m*16;

  __shared__ __attribute__((aligned(16))) unsigned short hb[16][72];
  __shared__ __attribute__((aligned(16))) unsigned short h2[16][72];
  int tid = threadIdx.x;
  int wave = tid>>6, lane = tid&63, ln16 = lane&15, quad = lane>>4;
  int r = wave*4 + quad;                  // node slot 0..15
  int row = row0 + r;
  int n = m*16 + r;
  int l = ln16;
  int p0 = rowptr[n], p1 = rowptr[n+1];
  const unsigned short* xb_ = xin + (size_t)b*NN*64;
  const float* wb = wp + (size_t)b*bstride;
  float a0=0.f, a1=0.f, a2=0.f, a3=0.f;
  #pragma unroll 4
  for (int p=p0; p<p1; ++p){
    int s = ssrc[p];
    float w = wb[p];
    uint2 mm = *(const uint2*)(xb_ + (size_t)s*64 + l*4);
    a0 += bf2f((unsigned short)(mm.x & 0xffffu)) * w;
    a1 += bf2f((unsigned short)(mm.x >> 16)) * w;
    a2 += bf2f((unsigned short)(mm.y & 0xffffu)) * w;
    a3 += bf2f((unsigned short)(mm.y >> 16)) * w;
  }
  float4 base = *(const float4*)(x + (size_t)row*64 + l*4);
  float o0=base.x+a0, o1=base.y+a1, o2=base.z+a2, o3=base.w+a3;
  float4 ov; ov.x=o0; ov.y=o1; ov.z=o2; ov.w=o3;
  *(float4*)(xe_out + (size_t)row*64 + l*4) = ov;
  *(uint2*)&hb[r][l*4] = make_uint2(pk2(o0,o1), pk2(o2,o3));
  __syncthreads();

  // MLP phase: block-wide 16-row tile; wave w -> output tile w (16 dims)
  int id = ntid[m*16 + ln16];
  bf16x8 xa0 = ld8bf(&hb[ln16][quad*8]);
  bf16x8 xa1 = ld8bf(&hb[ln16][32+quad*8]);
  bf16x8 xa2 = (quad<2) ? ld8f(emb + id*16 + quad*8) : zero8();
  float bb = b1[wave*16+ln16];
  f32x4 acc = (f32x4){bb,bb,bb,bb};
  acc = __builtin_amdgcn_mfma_f32_16x16x32_bf16(xa0, ld8bf(W1T + (wave*16+ln16)*96 + quad*8),      acc, 0,0,0);
  acc = __builtin_amdgcn_mfma_f32_16x16x32_bf16(xa1, ld8bf(W1T + (wave*16+ln16)*96 + 32 + quad*8), acc, 0,0,0);
  acc = __builtin_amdgcn_mfma_f32_16x16x32_bf16(xa2, ld8bf(W1T + (wave*16+ln16)*96 + 64 + quad*8), acc, 0,0,0);
  #pragma unroll
  for (int i=0;i<4;++i)
    h2[quad*4+i][wave*16+ln16] = f2bf(lrelu(acc[i]));
  __syncthreads();
  bf16x8 hh0 = ld8bf(&h2[ln16][quad*8]);
  bf16x8 hh1 = ld8bf(&h2[ln16][32+quad*8]);
  float b2v = b2[wave*16+ln16];
  f32x4 acc2 = (f32x4){b2v,b2v,b2v,b2v};
  acc2 = __builtin_amdgcn_mfma_f32_16x16x32_bf16(hh0, ld8bf(W2T + (wave*16+ln16)*64 + quad*8),      acc2, 0,0,0);
  acc2 = __builtin_amdgcn_mfma_f32_16x16x32_bf16(hh1, ld8bf(W2T + (wave*16+ln16)*64 + 32 + quad*8), acc2, 0,0,0);
  #pragma unroll
  for (int i=0;i<4;++i)
    out[(size_t)(row0+quad*4+i)*64 + wave*16+ln16] = f2bf(lrelu(acc2[i]));
}

// ---------------------------------------------------------------------------
// FUSED aggregation + uv projection, XCD-partitioned, global bf16 uv weights
// (LDS 2304B -> 8 blocks/CU). Grid 2504.
// ---------------------------------------------------------------------------
__global__ __launch_bounds__(256) void aggr_uv_kernel(
    const float* __restrict__ x,            // base [BN][64] f32
    const unsigned short* __restrict__ xin, // messages [BN][64] bf16
    const int* __restrict__ rowptr,
    const int* __restrict__ ssrc,
    const float* __restrict__ wp,           // wcsr (bstride 0)
    int bstride,
    const unsigned short* __restrict__ WT,  // [128][64] bf16 (prepped)
    unsigned short* __restrict__ uvp)       // [BN][128] bf16
{
  int u = blockIdx.x;
  int b = (u & 7) >> 1;
  int m = ((u >> 3) << 1) | (u & 1);
  if (m >= 625) return;
  int row0 = b*NN + m*16;

  __shared__ __attribute__((aligned(16))) unsigned short hb[16][72];
  int tid = threadIdx.x;
  int wave = tid>>6, lane = tid&63, ln16 = lane&15, quad = lane>>4;
  int r = wave*4 + quad;
  int row = row0 + r;
  int n = m*16 + r;
  int l = ln16;
  int p0 = rowptr[n], p1 = rowptr[n+1];
  const unsigned short* xb_ = xin + (size_t)b*NN*64;
  const float* wb = wp + (size_t)b*bstride;
  float a0=0.f, a1=0.f, a2=0.f, a3=0.f;
  #pragma unroll 4
  for (int p=p0; p<p1; ++p){
    int s = ssrc[p];
    float w = wb[p];
    uint2 mm = *(const uint2*)(xb_ + (size_t)s*64 + l*4);
    a0 += bf2f((unsigned short)(mm.x & 0xffffu)) * w;
    a1 += bf2f((unsigned short)(mm.x >> 16)) * w;
    a2 += bf2f((unsigned short)(mm.y & 0xffffu)) * w;
    a3 += bf2f((unsigned short)(mm.y >> 16)) * w;
  }
  float4 base = *(const float4*)(x + (size_t)row*64 + l*4);
  float o0=base.x+a0, o1=base.y+a1, o2=base.z+a2, o3=base.w+a3;
  *(uint2*)&hb[r][l*4] = make_uint2(pk2(o0,o1), pk2(o2,o3));
  __syncthreads();

  bf16x8 xa0 = ld8bf(&hb[ln16][quad*8]);
  bf16x8 xa1 = ld8bf(&hb[ln16][32+quad*8]);
  #pragma unroll
  for (int t=0;t<2;++t){
    int nt = wave*2 + t;   // output tile 0..7
    f32x4 acc = (f32x4){0.f,0.f,0.f,0.f};
    acc = __builtin_amdgcn_mfma_f32_16x16x32_bf16(xa0, ld8bf(WT + (nt*16+ln16)*64 + quad*8),      acc, 0,0,0);
    acc = __builtin_amdgcn_mfma_f32_16x16x32_bf16(xa1, ld8bf(WT + (nt*16+ln16)*64 + 32 + quad*8), acc, 0,0,0);
    #pragma unroll
    for (int i=0;i<4;++i)
      uvp[(size_t)(row0+quad*4+i)*128 + nt*16+ln16] = f2bf(acc[i]);
  }
}

// ---------------------------------------------------------------------------
// FUSED edge-gate + main-conv0 MLP: blocks 0-624 mlp2_g; 625..10632 gate
// (XCD-partitioned). Kernel LDS = 9216B (mlp2_body hb) -> gate blocks 8/CU.
// ---------------------------------------------------------------------------
__global__ __launch_bounds__(256) void gate_mlp2g_kernel(
    const unsigned short* __restrict__ uvp, // [BN][128] bf16
    const int* __restrict__ rowptr,
    const int* __restrict__ ssrc,
    const float* __restrict__ b1,           // [64]
    const float* __restrict__ W2g,          // [64]
    const float* __restrict__ b2,           // [1]
    float* __restrict__ gate,               // [B*E] f32, p-indexed
    const float* __restrict__ x,            // rnn
    const int* __restrict__ ntid,
    const float* __restrict__ emb,
    const unsigned short* __restrict__ wtg, // prepped g0 set
    const float* __restrict__ mb1, const float* __restrict__ mb2,
    unsigned short* __restrict__ mout)
{
  if (blockIdx.x < 625){
    mlp2_body(blockIdx.x, x, ntid, emb, wtg, mb1, wtg + 6144, mb2, mout);
    return;
  }
  int u = blockIdx.x;
  int b = (u & 7) >> 1;
  int m = (((u - 625) >> 3) << 1) | (u & 1);
  if (m >= 2500) return;
  int tid=threadIdx.x;
  int wave=tid>>6, lane=tid&63;
  int sub=lane>>4, l=lane&15;
  int n = m*4 + wave;
  int p0 = rowptr[n], p1 = rowptr[n+1];
  const unsigned short* ub = uvp + (size_t)b*NN*128;
  uint2 vu = *(const uint2*)(ub + (size_t)n*128 + 64 + l*4);
  float v0=bf2f((unsigned short)(vu.x&0xffffu)), v1=bf2f((unsigned short)(vu.x>>16));
  float v2=bf2f((unsigned short)(vu.y&0xffffu)), v3=bf2f((unsigned short)(vu.y>>16));
  float4 bb = *(const float4*)(b1 + l*4);
  float4 ww = *(const float4*)(W2g + l*4);
  float b2v = b2[0];
  float* gb = gate + (size_t)b*NE;
  #pragma unroll 4
  for (int p=p0+sub; p<p1; p+=4){
    int s = ssrc[p];
    uint2 uu = *(const uint2*)(ub + (size_t)s*128 + l*4);
    float h0 = lrelu(bf2f((unsigned short)(uu.x&0xffffu)) + v0 + bb.x);
    float h1 = lrelu(bf2f((unsigned short)(uu.x>>16))     + v1 + bb.y);
    float h2 = lrelu(bf2f((unsigned short)(uu.y&0xffffu)) + v2 + bb.z);
    float h3 = lrelu(bf2f((unsigned short)(uu.y>>16))     + v3 + bb.w);
    float part = h0*ww.x + h1*ww.y + h2*ww.z + h3*ww.w;
    part += __shfl_xor(part,1);
    part += __shfl_xor(part,2);
    part += __shfl_xor(part,4);
    part += __shfl_xor(part,8);
    if (l==0){
      float g = part + b2v;
      gb[p] = g>0.f ? g : 0.f;
    }
  }
}

// Last aggregation fused with both FC heads, XCD-partitioned batches:
// b = (u&7)>>1, m = (u>>3)*2+(u&1), guard m<2500. Grid 10008. Overwrites the
// d_out weight-scratch with final results (weights dead by now).
// ---------------------------------------------------------------------------
__global__ __launch_bounds__(256) void aggr_final_kernel(
    const float* x,                        // [BN][64] f32 (xg input)
    const unsigned short* __restrict__ xin,// [BN][64] bf16
    const int* __restrict__ rowptr,
    const int* __restrict__ ssrc,
    const float* __restrict__ wp,          // gate, stride NE
    const float* __restrict__ rnn,         // [BN][64]
    const float* __restrict__ Wr, const float* __restrict__ br,
    const float* __restrict__ Wg, const float* __restrict__ bg,
    float* __restrict__ out)               // [BN][7]
{
  int u = blockIdx.x;
  int b = (u & 7) >> 1;
  int m = ((u >> 3) << 1) | (u & 1);
  if (m >= 2500) return;

  __shared__ float sWr[448], sWg[448], sb[7];
  int tid=threadIdx.x;
  for (int i=tid;i<448;i+=256){ sWr[i]=Wr[i]; sWg[i]=Wg[i]; }
  if (tid<7) sb[tid]=br[tid]+bg[tid];
  __syncthreads();
  int wave=tid>>6, lane=tid&63;
  int sub=lane>>4, l=lane&15;
  int n = m*4 + wave;
  int bid = b*NN + n;
  int p0 = rowptr[n], p1 = rowptr[n+1];
  const unsigned short* xb_ = xin + (size_t)b*NN*64;
  const float* wb = wp + (size_t)b*NE;
  float a0=0.f, a1=0.f, a2=0.f, a3=0.f;
  #pragma unroll 4
  for (int p=p0+sub; p<p1; p+=4){
    int s = ssrc[p];
    float w = wb[p];
    uint2 mm = *(const uint2*)(xb_ + (size_t)s*64 + l*4);
    a0 += bf2f((unsigned short)(mm.x & 0xffffu)) * w;
    a1 += bf2f((unsigned short)(mm.x >> 16)) * w;
    a2 += bf2f((unsigned short)(mm.y & 0xffffu)) * w;
    a3 += bf2f((unsigned short)(mm.y >> 16)) * w;
  }
  a0 += __shfl_xor(a0,16); a0 += __shfl_xor(a0,32);
  a1 += __shfl_xor(a1,16); a1 += __shfl_xor(a1,32);
  a2 += __shfl_xor(a2,16); a2 += __shfl_xor(a2,32);
  a3 += __shfl_xor(a3,16); a3 += __shfl_xor(a3,32);
  if (sub==0){
    float4 base = *(const float4*)(x + (size_t)bid*64 + l*4);
    float o0=base.x+a0, o1=base.y+a1, o2=base.z+a2, o3=base.w+a3;
    float4 rr = *(const float4*)(rnn + (size_t)bid*64 + l*4);
    float part[7];
    #pragma unroll
    for (int q=0;q<7;++q)
      part[q] = o0*sWg[(l*4+0)*7+q] + o1*sWg[(l*4+1)*7+q]
              + o2*sWg[(l*4+2)*7+q] + o3*sWg[(l*4+3)*7+q]
              + rr.x*sWr[(l*4+0)*7+q] + rr.y*sWr[(l*4+1)*7+q]
              + rr.z*sWr[(l*4+2)*7+q] + rr.w*sWr[(l*4+3)*7+q];
    #pragma unroll
    for (int q=0;q<7;++q){
      part[q] += __shfl_xor(part[q],1);
      part[q] += __shfl_xor(part[q],2);
      part[q] += __shfl_xor(part[q],4);
      part[q] += __shfl_xor(part[q],8);
    }
    if (l==0){
      #pragma unroll
      for (int q=0;q<7;++q) out[(size_t)bid*7+q] = part[q] + sb[q];
    }
  }
}

// ---------------------------------------------------------------------------
extern "C" void kernel_launch(void* const* d_in, const int* in_sizes, int n_in,
                              void* d_out, int out_size, void* d_ws, size_t ws_size,
                              hipStream_t stream)
{
  (void)in_sizes; (void)n_in; (void)out_size; (void)ws_size;
  const float* input_day = (const float*)d_in[0];
  const int* ei    = (const int*)d_in[1];
  const int* ntid  = (const int*)d_in[2];
  const float* edge_attr = (const float*)d_in[3];
  const float* gWx = (const float*)d_in[4];
  const float* gWh = (const float*)d_in[5];
  const float* gbx = (const float*)d_in[6];
  const float* gbh = (const float*)d_in[7];
  const float* rW  = (const float*)d_in[8];
  const float* rb  = (const float*)d_in[9];
  const float* eemb= (const float*)d_in[10];
  const float* gemb= (const float*)d_in[11];
  const float* ec0W1=(const float*)d_in[12];
  const float* ec0b1=(const float*)d_in[13];
  const float* ec0W2=(const float*)d_in[14];
  const float* ec0b2=(const float*)d_in[15];
  const float* ec1W1=(const float*)d_in[16];
  const float* ec1b1=(const float*)d_in[17];
  const float* ec1W2=(const float*)d_in[18];
  const float* ec1b2=(const float*)d_in[19];
  const float* gc0W1=(const float*)d_in[20];
  const float* gc0b1=(const float*)d_in[21];
  const float* gc0W2=(const float*)d_in[22];
  const float* gc0b2=(const float*)d_in[23];
  const float* gc1W1=(const float*)d_in[24];
  const float* gc1b1=(const float*)d_in[25];
  const float* gc1W2=(const float*)d_in[26];
  const float* gc1b2=(const float*)d_in[27];
  const float* efmW1=(const float*)d_in[28];
  const float* efmb1=(const float*)d_in[29];
  const float* efmW2=(const float*)d_in[30];
  const float* efmb2=(const float*)d_in[31];
  const float* gcnW =(const float*)d_in[32];
  const float* gcnb =(const float*)d_in[33];

  // Workspace layout — ~43.6 MB (known-good envelope), with region reuse:
  //   gat region doubles as xin_B (EdgeNet conv1 messages, pre-gate)
  //   uvp region doubles as xin_D (main conv1 messages, post-gate)
  // Prepped bf16 weight tables (96KB) live in d_out (write-only output,
  //   1.12MB) — dead before aggr_final overwrites it with results.
  char* ws = (char*)d_ws;
  float*          rnn = (float*)(ws);                      // 10,240,000 B
  float*          xe  = (float*)(ws + 10240000);           // 10,240,000 B
  unsigned short* xinA= (unsigned short*)(ws + 20480000);  //  5,120,000 B
  unsigned short* uvp = (unsigned short*)(ws + 25600000);  // 10,240,000 B
  float*          gat = (float*)(ws + 35840000);           //  5,120,000 B (p-indexed)
  int* rowptr= (int*)(ws + 40960000);                      //     40,004 B
  int* cursor= (int*)(ws + 41000064);                      //     40,000 B
  int* counts= (int*)(ws + 41040064);                      //     40,000 B
  int*   ssrc= (int*)(ws + 41080064);                      //  1,280,000 B
  float* wcsr= (float*)(ws + 42360064);                    //  1,280,000 B -> 43,640,064
  unsigned short* xinB = (unsigned short*)gat;             // alias (pre-gate)
  unsigned short* xinD = (unsigned short*)uvp;             // alias (post-gate)
  unsigned short* wt   = (unsigned short*)d_out;           // prepped weights (96KB scratch)

  // CSR build + GRU + weight-prep, horizontally fused
  hipMemsetAsync(counts, 0, NN*sizeof(int), stream);
  // gru (0-624) || count (625-1874) || weight-prep (1875-1882)
  gru_count_kernel<<<1883, 256, 0, stream>>>(input_day, gWx, gWh, gbx, gbh, rnn,
                                             ei, counts,
                                             ec0W1, ec0W2, ec1W1, ec1W2,
                                             gc0W1, gc0W2, gc1W1, gc1W2,
                                             efmW1, wt);
  scan_kernel<<<1, 1024, 0, stream>>>(counts, rowptr, cursor);
  // mlp2_e (0-624, rnn->xinA, e0 weights) || fill (625-1874)
  fill_mlp2e_kernel<<<1875, 256, 0, stream>>>(ei, edge_attr, cursor, ssrc, wcsr,
                                              rnn, ntid, eemb,
                                              wt, ec0b1, ec0b2, xinA);
  // EdgeNet: conv0 aggregation fused with conv1 MLP (e1 weights) -> xe1 + xin_B
  aggr_mlp_kernel<<<2504, 256, 0, stream>>>(rnn, xinA, rowptr, ssrc, wcsr, 0,
                                            ntid, eemb,
                                            wt + WT_SET, ec1b1, wt + WT_SET + 6144, ec1b2,
                                            xe, xinB);
  // EdgeNet conv1 aggregation fused with uv projection -> uvp
  aggr_uv_kernel<<<2504, 256, 0, stream>>>(xe, xinB, rowptr, ssrc, wcsr, 0,
                                           wt + WT_UV, uvp);
  // mlp2_g (0-624, g0 weights, rnn->xinA) || gate (625-10632, -> gat)
  gate_mlp2g_kernel<<<10633, 256, 0, stream>>>(uvp, rowptr, ssrc,
                                               efmb1, efmW2, efmb2, gat,
                                               rnn, ntid, gemb,
                                               wt + 2*WT_SET, gc0b1, gc0b2, xinA);
  // Main conv0 aggregation (gated) fused with conv1 MLP (g1 weights) -> xe + xin_D
  aggr_mlp_kernel<<<2504, 256, 0, stream>>>(rnn, xinA, rowptr, ssrc, gat, NE,
                                            ntid, gemb,
                                            wt + 3*WT_SET, gc1b1, wt + 3*WT_SET + 6144, gc1b2,
                                            xe, xinD);
  // last aggregation fused with both FC heads -> d_out (overwrites weight scratch)
  aggr_final_kernel<<<10008, 256, 0, stream>>>(xe, xinD, rowptr, ssrc, gat, rnn,
                                               rW, rb, gcnW, gcnb, (float*)d_out);
}